// Round 1
// baseline (648.479 us; speedup 1.0000x reference)
//
#include <hip/hip_runtime.h>
#include <math.h>

#define NTOK   32768
#define HDIM   1024
#define NEXP   64
#define NE     (NTOK * NEXP)
#define CAP    512
#define HC     64
#define TB     64
#define TIECAP 2048

__device__ __forceinline__ unsigned f2key(float f) {
  unsigned u = __float_as_uint(f);
  return (u & 0x80000000u) ? ~u : (u | 0x80000000u);
}

__global__ void init_kernel(unsigned* cnt, float* sumP) {
  int i = threadIdx.x;
  if (i < NEXP) { cnt[i] = 0u; sumP[i] = 0.f; }
}

// One block = 64 tokens x 64 experts. 4 waves; each wave handles 16 tokens,
// lane = expert. LDS: x tile [64][64] + w tile [64][68] (pad -> conflict-free
// b128 reads at stride 68 floats).
__global__ __launch_bounds__(256) void router_kernel(
    const float* __restrict__ x, const float* __restrict__ w,
    float* __restrict__ probs, unsigned* __restrict__ keyNE,
    unsigned* __restrict__ keyEN, unsigned long long* __restrict__ assignB,
    unsigned* __restrict__ cnt, float* __restrict__ sumP,
    float* __restrict__ out) {
  __shared__ float sm[TB * HC + NEXP * (HC + 4)];
  float* xs = sm;
  float* wt = sm + TB * HC;
  const int tid  = threadIdx.x;
  const int wid  = tid >> 6;
  const int lane = tid & 63;
  const int t0   = blockIdx.x * TB;

  float acc[16];
#pragma unroll
  for (int i = 0; i < 16; ++i) acc[i] = 0.f;

  for (int hc = 0; hc < HDIM / HC; ++hc) {
    const int h0 = hc * HC;
    {
      int idx = tid;
#pragma unroll
      for (int r = 0; r < 4; ++r, idx += 256) {   // 1024 float4s of x
        int t = idx >> 4, j4 = idx & 15;
        float4 v = *(const float4*)(x + (size_t)(t0 + t) * HDIM + h0 + j4 * 4);
        *(float4*)(xs + t * HC + j4 * 4) = v;
      }
      idx = tid;
#pragma unroll
      for (int r = 0; r < 4; ++r, idx += 256) {   // 1024 float4s of w
        int e = idx >> 4, j4 = idx & 15;
        float4 v = *(const float4*)(w + (size_t)e * HDIM + h0 + j4 * 4);
        *(float4*)(wt + e * (HC + 4) + j4 * 4) = v;
      }
    }
    __syncthreads();
    const float4* wrow = (const float4*)(wt + lane * (HC + 4));
    const float4* xrow = (const float4*)(xs + (wid * 16) * HC);
#pragma unroll
    for (int j4 = 0; j4 < 16; ++j4) {
      float4 wv = wrow[j4];
#pragma unroll
      for (int i = 0; i < 16; ++i) {
        float4 xv = xrow[i * 16 + j4];
        acc[i] += wv.x * xv.x + wv.y * xv.y + wv.z * xv.z + wv.w * xv.w;
      }
    }
    __syncthreads();
  }

  unsigned* kt = (unsigned*)sm;  // reuse LDS: [64 tokens][65] keys for transpose
  for (int i = 0; i < 16; ++i) {
    const int tb = wid * 16 + i;
    const int t  = t0 + tb;
    float l = acc[i];
    float mx = l;
#pragma unroll
    for (int m = 1; m < 64; m <<= 1) mx = fmaxf(mx, __shfl_xor(mx, m));
    float ex = expf(l - mx);
    float s = ex;
#pragma unroll
    for (int m = 1; m < 64; m <<= 1) s += __shfl_xor(s, m);
    float p = ex / s;
    // rank (stable: ties -> lower index first) and csum at own sorted position
    int rank = 0; float csum = p;
    for (int d = 1; d < 64; ++d) {
      int j = (lane + d) & 63;
      float pj = __shfl(p, j);
      bool gt = (pj > p) || (pj == p && j < lane);
      rank += gt ? 1 : 0;
      csum += gt ? pj : 0.f;
    }
    int kc = (csum >= 0.9f) ? rank : 63;
#pragma unroll
    for (int m = 1; m < 64; m <<= 1) kc = min(kc, __shfl_xor(kc, m));
    const bool assign = (rank <= kc);
    float R = assign ? (p - (float)(rank + 1)) : -1e9f;
    unsigned key = f2key(R);
    probs[(size_t)t * NEXP + lane] = p;
    keyNE[(size_t)t * NEXP + lane] = key;
    kt[tb * 65 + lane] = key;
    unsigned long long ab = __ballot(assign);
    if (lane == 0) assignB[t] = ab;
    if (rank == 0) {
      out[(size_t)2 * NE + 1 + t] = (float)lane;  // top1_idx output
      atomicAdd(&cnt[lane], 1u);
      atomicAdd(&sumP[lane], p);
    }
  }
  __syncthreads();
#pragma unroll
  for (int r = 0; r < 16; ++r) {                  // coalesced [E][N] key write
    int e = wid * 16 + r;
    keyEN[(size_t)e * NTOK + t0 + lane] = kt[lane * 65 + e];
  }
}

// One block per expert: 4-pass MSB radix select for C-th largest key,
// then exact lowest-token-index tie resolution at the boundary value.
__global__ __launch_bounds__(512) void select_kernel(
    const unsigned* __restrict__ keyEN, unsigned* __restrict__ theta,
    int* __restrict__ tieCut, int* __restrict__ tieBuf) {
  const int e = blockIdx.x;
  const unsigned* col = keyEN + (size_t)e * NTOK;
  const int tid = threadIdx.x;
  __shared__ unsigned hist[256];
  __shared__ unsigned s_prefix, s_need, s_m, s_tn;
  __shared__ int s_cut;
  if (tid == 0) { s_prefix = 0u; s_need = CAP; }
  __syncthreads();
  for (int pass = 0; pass < 4; ++pass) {
    const int shift = 24 - 8 * pass;
    if (tid < 256) hist[tid] = 0u;
    __syncthreads();
    const unsigned prefix = s_prefix;
    for (int t = tid; t < NTOK; t += 512) {
      unsigned k = col[t];
      bool match = (pass == 0) || ((k >> (shift + 8)) == (prefix >> (shift + 8)));
      if (match) atomicAdd(&hist[(k >> shift) & 255u], 1u);
    }
    __syncthreads();
    if (tid == 0) {
      unsigned need = s_need, cum = 0u;
      for (int d = 255; d >= 0; --d) {
        unsigned c = hist[d];
        if (cum + c >= need) {
          s_prefix = prefix | ((unsigned)d << shift);
          s_need = need - cum;
          s_m = c;
          break;
        }
        cum += c;
      }
    }
    __syncthreads();
  }
  const unsigned th = s_prefix;
  const unsigned need = s_need;
  const unsigned m = s_m;
  const unsigned UNASS = f2key(-1e9f);
  int cut;
  if (th == UNASS) {
    cut = -1;  // boundary sits among unassigned tokens; assign-mask kills them
  } else if (m == need) {
    cut = 0x7fffffff;  // keep all boundary ties
  } else {
    if (tid == 0) s_tn = 0u;
    __syncthreads();
    int* buf = tieBuf + e * TIECAP;
    for (int t = tid; t < NTOK; t += 512) {
      if (col[t] == th) {
        unsigned i = atomicAdd(&s_tn, 1u);
        if (i < TIECAP) buf[i] = t;
      }
    }
    __syncthreads();
    int mm = (int)min(s_tn, (unsigned)TIECAP);
    for (int i = tid; i < mm; i += 512) {
      int ti = buf[i];
      int less = 0;
      for (int j = 0; j < mm; ++j) less += (buf[j] < ti) ? 1 : 0;
      if (less == (int)need - 1) s_cut = ti;  // need-th smallest index
    }
    __syncthreads();
    cut = s_cut;
  }
  if (tid == 0) { theta[e] = th; tieCut[e] = cut; }
}

__global__ __launch_bounds__(256) void write_kernel(
    const float* __restrict__ probs, const unsigned* __restrict__ keyNE,
    const unsigned long long* __restrict__ assignB,
    const unsigned* __restrict__ theta, const int* __restrict__ tieCut,
    float* __restrict__ out) {
  const int id = blockIdx.x * 256 + threadIdx.x;
  const int t = id >> 6, e = id & 63;
  unsigned k = keyNE[id];
  float p = probs[id];
  bool a = (assignB[t] >> e) & 1ull;
  unsigned th = theta[e];
  int cut = tieCut[e];
  bool keep = (k > th) || ((k == th) && (t <= cut));
  bool msk = a && keep;
  out[id] = msk ? 1.f : 0.f;
  out[(size_t)NE + id] = msk ? p : 0.f;
}

__global__ void aux_kernel(const unsigned* __restrict__ cnt,
                           const float* __restrict__ sumP,
                           float* __restrict__ out) {
  int e = threadIdx.x;
  float v = ((float)cnt[e] / (float)NTOK) * (sumP[e] / (float)NTOK);
#pragma unroll
  for (int m = 1; m < 64; m <<= 1) v += __shfl_xor(v, m);
  if (e == 0) out[(size_t)2 * NE] = (float)NEXP * v * 0.01f;
}

extern "C" void kernel_launch(void* const* d_in, const int* in_sizes, int n_in,
                              void* d_out, int out_size, void* d_ws, size_t ws_size,
                              hipStream_t stream) {
  const float* x = (const float*)d_in[0];
  const float* w = (const float*)d_in[1];
  float* out = (float*)d_out;

  char* ws = (char*)d_ws;
  float* probs                 = (float*)ws;                       // NE f32
  unsigned* keyNE              = (unsigned*)(probs + NE);          // NE u32
  unsigned* keyEN              = keyNE + NE;                       // NE u32
  unsigned long long* assignB  = (unsigned long long*)(keyEN + NE);// NTOK u64
  unsigned* cnt                = (unsigned*)(assignB + NTOK);      // 64
  float* sumP                  = (float*)(cnt + NEXP);             // 64
  unsigned* theta              = (unsigned*)(sumP + NEXP);         // 64
  int* tieCut                  = (int*)(theta + NEXP);             // 64
  int* tieBuf                  = tieCut + NEXP;                    // 64*TIECAP

  init_kernel<<<1, 64, 0, stream>>>(cnt, sumP);
  router_kernel<<<NTOK / TB, 256, 0, stream>>>(x, w, probs, keyNE, keyEN,
                                               assignB, cnt, sumP, out);
  select_kernel<<<NEXP, 512, 0, stream>>>(keyEN, theta, tieCut, tieBuf);
  write_kernel<<<NE / 256, 256, 0, stream>>>(probs, keyNE, assignB, theta,
                                             tieCut, out);
  aux_kernel<<<1, 64, 0, stream>>>(cnt, sumP, out);
}